// Round 11
// baseline (385.059 us; speedup 1.0000x reference)
//
#include <hip/hip_runtime.h>

#define D_MODEL 512
#define SEQ     4096
#define BATCH   4
#define M_TOT   (BATCH*SEQ)   // 16384
#define NT      (SEQ/32)      // 128 key tiles
#define WS_NEEDED ((size_t)2 * M_TOT * D_MODEL * 2)   // node_bf + nodeT_bf: 32 MiB

typedef float  f32x4  __attribute__((ext_vector_type(4)));
typedef __bf16 bf16x8 __attribute__((ext_vector_type(8)));

// lgkm-only barrier: syncs LDS data across waves WITHOUT draining vmcnt,
// so in-flight global_load_lds prefetches survive across it.
#define LGKM_BARRIER() asm volatile("s_waitcnt lgkmcnt(0)\n\ts_barrier" ::: "memory")

union FU { float f; unsigned int u; };
__device__ __forceinline__ unsigned short f_to_bf16(float f) {
    FU c; c.f = f;
    unsigned int r = c.u + 0x7fffu + ((c.u >> 16) & 1u);   // RNE
    return (unsigned short)(r >> 16);
}

// split fp32 pair -> packed hi (truncated top16) + packed lo (RNE bf16 of
// exact residual). hi+lo reproduces x to ~2^-17 relative.
__device__ __forceinline__ void split_pack(float f0, float f1,
        unsigned int& hp, unsigned int& lp) {
    FU u0, u1; u0.f = f0; u1.f = f1;
    unsigned int h0 = u0.u & 0xFFFF0000u, h1 = u1.u & 0xFFFF0000u;
    hp = (h0 >> 16) | h1;
    FU t0, t1; t0.u = h0; t1.u = h1;
    float l0 = f0 - t0.f, l1 = f1 - t1.f;       // exact (Sterbenz)
    lp = (unsigned)f_to_bf16(l0) | ((unsigned)f_to_bf16(l1) << 16);
}

// ---- DPP cross-lane (VALU pipe, NOT the DS pipe like __shfl_xor) ----
// 16-lane butterfly, pairings commutative-identical to shfl_xor(1,2,4,8):
// results BITWISE identical to a shfl tree.
template<int CTRL>
__device__ __forceinline__ float dpp_mov(float x) {
    union { float f; int i; } u, r;
    u.f = x;
    r.i = __builtin_amdgcn_update_dpp(u.i, u.i, CTRL, 0xF, 0xF, false);
    return r.f;
}
__device__ __forceinline__ float red_max16(float x) {
    x = fmaxf(x, dpp_mov<0xB1>(x));
    x = fmaxf(x, dpp_mov<0x4E>(x));
    x = fmaxf(x, dpp_mov<0x141>(x));
    x = fmaxf(x, dpp_mov<0x140>(x));
    return x;
}
__device__ __forceinline__ float red_sum16(float x) {
    x += dpp_mov<0xB1>(x);
    x += dpp_mov<0x4E>(x);
    x += dpp_mov<0x141>(x);
    x += dpp_mov<0x140>(x);
    return x;
}

// -------- K1: node_bf = relu(x @ W^T + b) (bf16), + transposed copy --------
// v11: LDS-FREE split-bf16 MFMA GEMM. v7's counters/model showed the hi/lo
// split staging (4 bf16 tiles, ~2048 b128 ds_writes per block per kc-step)
// made proj DS-pipe-bound (~115us vs ~11us MFMA work). The MFMA fragment
// layout (lane lr, quad q -> x[row][kc+q*8..+7], 32B contiguous) can be
// loaded DIRECTLY from global (L2-resident; 2x wave duplication absorbed
// by L2). Split hi/lo in registers. No LDS, no barriers in the k-loop;
// register ping-pong (A/B sets, static indexing) software-pipelines the
// L2 latency under the MFMAs.
// Split values, MFMA order, epilogue identical to v7 -> node_bf bit-exact.
extern "C" __global__ __launch_bounds__(256, 2) void proj_kernel(
        const float* __restrict__ x, const float* __restrict__ w,
        const float* __restrict__ bias,
        unsigned short* __restrict__ node_bf, unsigned short* __restrict__ nodeT_bf) {
    const int tid  = threadIdx.x;
    const int lane = tid & 63;
    const int wv   = tid >> 6;        // 0..3
    const int lr   = lane & 15;
    const int quad = lane >> 4;
    const int row0 = blockIdx.x * 128;
    const int col0 = blockIdx.y * 128;
    const int wm   = (wv & 1) * 64;
    const int wn   = (wv >> 1) * 64;

    // per-lane fragment base pointers (8 contiguous fp32 each)
    const float* xb = x + (size_t)(row0 + wm + lr)*D_MODEL + quad*8;
    const float* wb = w + (size_t)(col0 + wn + lr)*D_MODEL + quad*8;

    f32x4 acc[4][4];
    #pragma unroll
    for (int i = 0; i < 4; ++i)
        #pragma unroll
        for (int j = 0; j < 4; ++j) acc[i][j] = (f32x4){0.f,0.f,0.f,0.f};

    // load + in-register split of one kc-step's fragments (A: 4 row-frags,
    // B: 4 col-frags; 8 fp32 each -> hi/lo bf16x8 pairs)
    auto load_split = [&](int kc, bf16x8 ah[4], bf16x8 al[4],
                                  bf16x8 bh[4], bf16x8 bl[4]) {
        #pragma unroll
        for (int i = 0; i < 4; ++i) {
            const float* p = xb + (size_t)i*16*D_MODEL + kc;
            float4 r0 = *(const float4*)(p);
            float4 r1 = *(const float4*)(p + 4);
            uint4 h, l;
            split_pack(r0.x, r0.y, h.x, l.x);
            split_pack(r0.z, r0.w, h.y, l.y);
            split_pack(r1.x, r1.y, h.z, l.z);
            split_pack(r1.z, r1.w, h.w, l.w);
            ah[i] = *(bf16x8*)&h;  al[i] = *(bf16x8*)&l;
        }
        #pragma unroll
        for (int j = 0; j < 4; ++j) {
            const float* p = wb + (size_t)j*16*D_MODEL + kc;
            float4 r0 = *(const float4*)(p);
            float4 r1 = *(const float4*)(p + 4);
            uint4 h, l;
            split_pack(r0.x, r0.y, h.x, l.x);
            split_pack(r0.z, r0.w, h.y, l.y);
            split_pack(r1.x, r1.y, h.z, l.z);
            split_pack(r1.z, r1.w, h.w, l.w);
            bh[j] = *(bf16x8*)&h;  bl[j] = *(bf16x8*)&l;
        }
    };
    auto mfma_all = [&](bf16x8 ah[4], bf16x8 al[4], bf16x8 bh[4], bf16x8 bl[4]) {
        #pragma unroll
        for (int i = 0; i < 4; ++i)
            #pragma unroll
            for (int j = 0; j < 4; ++j) {
                acc[i][j] = __builtin_amdgcn_mfma_f32_16x16x32_bf16(al[i], bh[j], acc[i][j], 0, 0, 0);
                acc[i][j] = __builtin_amdgcn_mfma_f32_16x16x32_bf16(ah[i], bl[j], acc[i][j], 0, 0, 0);
                acc[i][j] = __builtin_amdgcn_mfma_f32_16x16x32_bf16(ah[i], bh[j], acc[i][j], 0, 0, 0);
            }
    };

    // register ping-pong: set A computes kc, set B computes kc+32 (named
    // sets + unrolled-by-2 loop keep every index compile-time, rule #20)
    bf16x8 ahA[4], alA[4], bhA[4], blA[4];
    bf16x8 ahB[4], alB[4], bhB[4], blB[4];
    load_split(0, ahA, alA, bhA, blA);
    for (int kc = 0; kc < D_MODEL; kc += 64) {
        load_split(kc + 32, ahB, alB, bhB, blB);   // kc+32 <= 480 always
        mfma_all(ahA, alA, bhA, blA);
        if (kc + 64 < D_MODEL) load_split(kc + 64, ahA, alA, bhA, blA);
        mfma_all(ahB, alB, bhB, blB);
    }

    // epilogue: +bias, relu, RNE->bf16, write node + transposed copy.
    // C/D layout (m89): row = quad*4 + r, col = lr.
    #pragma unroll
    for (int j = 0; j < 4; ++j) {
        int col = col0 + wn + j*16 + lr;
        float bv = bias[col];
        #pragma unroll
        for (int i = 0; i < 4; ++i) {
            #pragma unroll
            for (int r = 0; r < 4; ++r) {
                float v = acc[i][j][r] + bv;
                v = v > 0.0f ? v : 0.0f;
                unsigned short us = f_to_bf16(v);
                int row = row0 + wm + i*16 + quad*4 + r;
                node_bf[(size_t)row*D_MODEL + col] = us;
                int b = row >> 12, si = row & 4095;
                nodeT_bf[((size_t)(b*D_MODEL + col))*SEQ + si] = us;
            }
        }
    }
}

// -------- K2: flash attention via MFMA, out(fp32) --------
// v10 (PROVEN 244us): diagonal prepass + sequential tile order (L2
// sharing), data-independent tile skip (jm <= m_run - 25), lazy V staging
// (block-uniform), single-buffered Vt, DPP softmax, setprio, lgkm-only
// mid-iter barriers. UNCHANGED this round.
// LDS: 65536 (Ks) + 32768 (Vt) + 5120 (Ps) + 512 (Sm) + 32 (Lf) = 103968 B
extern "C" __global__ __launch_bounds__(512, 2) void flash_kernel(
        const unsigned short* __restrict__ node,
        const unsigned short* __restrict__ nodeT,
        float* __restrict__ out) {
    __shared__ unsigned short Ks[2][32][512];   // [buf][key][d]
    __shared__ unsigned short Vt[512][32];      // [d][key], single buffer
    __shared__ unsigned short Ps[4][16][40];    // [qg][qrow][key], +8 pad
    __shared__ float          Sm[4][2][16];     // [qg][kh][row] exchange buffer
    __shared__ int            Lf[8];            // per-wave live flags
    const int tid  = threadIdx.x;
    const int lane = tid & 63;
    const int wv   = tid >> 6;        // 0..7
    const int qg   = wv & 3;          // qrow group
    const int kh   = wv >> 2;         // key half (QK) / d half (PV)
    const int lr   = lane & 15;
    const int quad = lane >> 4;
    const int bb   = blockIdx.y;
    const int q0   = blockIdx.x * 64;
    const int ktd  = blockIdx.x * 2;  // first of the two diagonal tiles

    const unsigned short* nb  = node  + (size_t)bb * SEQ * D_MODEL;
    const unsigned short* ntb = nodeT + (size_t)bb * D_MODEL * SEQ;

    // Q fragments: A[m=lr][k = t*32 + quad*8 + j]
    bf16x8 qf[16];
    const int qrow = q0 + qg*16 + lr;
    #pragma unroll
    for (int t = 0; t < 16; ++t)
        qf[t] = *reinterpret_cast<const bf16x8*>(&nb[(size_t)qrow*D_MODEL + t*32 + quad*8]);

    f32x4 o[16];                      // 16 qrows x 256 d (own half)
    #pragma unroll
    for (int n = 0; n < 16; ++n) o[n] = (f32x4){0.f,0.f,0.f,0.f};
    float m_run[4] = {-3.0e38f,-3.0e38f,-3.0e38f,-3.0e38f};
    float l_run[4] = {0.f,0.f,0.f,0.f};

    // tile order: [ktd, ktd+1, 0, 1, ..., 127] (prepass then sequential)
    auto ktOf = [&](int i) { return i < 2 ? ktd + i : i - 2; };

    // stage K tile kt into buffer buf (8 waves x 4 rows).
    auto stageK = [&](int kt, int buf) {
        #pragma unroll
        for (int i = 0; i < 4; ++i) {
            int r = wv*4 + i;
            const unsigned short* g = nb + (size_t)(kt*32 + r)*D_MODEL + ((lane ^ (r & 7)) << 3);
            __builtin_amdgcn_global_load_lds(
                (const __attribute__((address_space(1))) unsigned int*)g,
                (__attribute__((address_space(3))) unsigned int*)&Ks[buf][r][0],
                16, 0, 0);
        }
    };
    // stage V tile kt into the single Vt buffer (8 waves x 4 chunks).
    auto stageV = [&](int kt) {
        #pragma unroll
        for (int i = 0; i < 4; ++i) {
            int d0 = (wv*4 + i) * 16;
            int d  = d0 + (lane >> 2);
            const unsigned short* g = ntb + (size_t)d*SEQ + kt*32 + ((((lane & 3) ^ (d & 3))) << 3);
            __builtin_amdgcn_global_load_lds(
                (const __attribute__((address_space(1))) unsigned int*)g,
                (__attribute__((address_space(3))) unsigned int*)&Vt[d0][0],
                16, 0, 0);
        }
    };

    stageK(ktOf(0), 0);
    __syncthreads();           // drains vmcnt: tile 0 resident

    const int kxor = lr & 7;   // K read swizzle ((kh*16+lr)&7 == lr&7)
    const int vxor = lr & 3;   // V read swizzle ((dblk*16+lr)&3 == lr&3)

    for (int idx = 0; idx < NT + 2; ++idx) {
        const int cur = idx & 1;
        const int kt  = ktOf(idx);
        // diag tiles already accumulated by the prepass -> force-skip later
        const bool force = (idx >= 2) && ((kt >> 1) == blockIdx.x);
        // issue next K tile's loads now; in flight across both lgkm-only
        // barriers, drained by end-of-iter __syncthreads.
        if (idx + 1 < NT + 2) stageK(ktOf(idx + 1), cur ^ 1);

        // S half = Q K^T (16 qrows x own 16 keys); swizzled K read
        f32x4 sacc = (f32x4){0.f,0.f,0.f,0.f};
        __builtin_amdgcn_s_setprio(1);
        #pragma unroll
        for (int t = 0; t < 16; ++t) {
            bf16x8 kb = *reinterpret_cast<const bf16x8*>(
                &Ks[cur][kh*16 + lr][(((t<<2)|quad) ^ kxor) << 3]);
            sacc = __builtin_amdgcn_mfma_f32_16x16x32_bf16(qf[t], kb, sacc, 0, 0, 0);
        }
        __builtin_amdgcn_s_setprio(0);

        // local 16-lane max per row (DPP tree, VALU pipe); post to exchange
        float mx[4];
        #pragma unroll
        for (int r = 0; r < 4; ++r) mx[r] = red_max16(sacc[r]);
        if (lr == 0) {
            #pragma unroll
            for (int r = 0; r < 4; ++r) Sm[qg][kh][quad*4 + r] = mx[r];
        }
        LGKM_BARRIER();   // #1: Sm visible (vmcnt untouched) -- unconditional

        // joint per-row max over all 32 keys; tile-skip decision.
        float jm[4];
        bool live = false;
        #pragma unroll
        for (int r = 0; r < 4; ++r) {
            jm[r] = fmaxf(mx[r], Sm[qg][kh ^ 1][quad*4 + r]);
            live = live || (jm[r] > m_run[r] - 25.0f);
        }
        // wave-uniform; kh pair agrees (same jm, same m_run evolution)
        const bool skip = force || !__any(live);

        if (!skip) {
            float alpha[4];
            #pragma unroll
            for (int r = 0; r < 4; ++r) {
                float mnew = fmaxf(m_run[r], jm[r]);
                alpha[r]   = __expf(m_run[r] - mnew);
                float p    = __expf(sacc[r] - mnew);
                m_run[r]   = mnew;
                Ps[qg][quad*4 + r][kh*16 + lr] = f_to_bf16(p);
                float rs   = red_sum16(p);
                l_run[r] = l_run[r]*alpha[r] + rs;
            }
            // skip O-rescale when every alpha is exactly 1.0 (bit-exact skip)
            bool need = !(alpha[0]==1.f && alpha[1]==1.f && alpha[2]==1.f && alpha[3]==1.f);
            if (__any(need)) {
                #pragma unroll
                for (int n = 0; n < 16; ++n) {
                    #pragma unroll
                    for (int r = 0; r < 4; ++r) o[n][r] *= alpha[r];
                }
            }
        }
        if (lane == 0) Lf[wv] = skip ? 0 : 1;   // post live bit
        LGKM_BARRIER();   // #2: Ps + Lf visible -- unconditional

        // block-uniform: does ANY wave need V for this tile?
        const bool block_live = (Lf[0]|Lf[1]|Lf[2]|Lf[3]|Lf[4]|Lf[5]|Lf[6]|Lf[7]) != 0;
        if (block_live) {
            stageV(kt);
            // all-or-none (block-uniform condition). Emits
            // s_waitcnt vmcnt(0) lgkmcnt(0) + s_barrier: V DMA landed
            // before PV reads; K prefetch (long since covered) also drains.
            __syncthreads();
            if (!skip) {
                // P fragment: A[m=lr][k=quad*8+j], full 32 keys
                bf16x8 pa = *reinterpret_cast<const bf16x8*>(&Ps[qg][lr][quad*8]);
                // PV: own 16 d-blocks (d = kh*256 ..), swizzled V read
                __builtin_amdgcn_s_setprio(1);
                #pragma unroll
                for (int n = 0; n < 16; ++n) {
                    int dblk = kh*16 + n;
                    bf16x8 vb = *reinterpret_cast<const bf16x8*>(
                        &Vt[dblk*16 + lr][(quad ^ vxor) << 3]);
                    o[n] = __builtin_amdgcn_mfma_f32_16x16x32_bf16(pa, vb, o[n], 0, 0, 0);
                }
                __builtin_amdgcn_s_setprio(0);
            }
        }

        // end-of-iter barrier: drains vmcnt (next K tile resident) and
        // closes this iter's LDS reads before buffers are reused.
        __syncthreads();
    }

    // final l = own half + partner half (alpha sequence was shared)
    if (lr == 0) {
        #pragma unroll
        for (int r = 0; r < 4; ++r) Sm[qg][kh][quad*4 + r] = l_run[r];
    }
    __syncthreads();
    #pragma unroll
    for (int r = 0; r < 4; ++r) {
        float l_tot = l_run[r] + Sm[qg][kh ^ 1][quad*4 + r];
        float inv   = 1.0f / l_tot;
        int row = q0 + qg*16 + quad*4 + r;
        float* obase = out + ((size_t)bb * SEQ + row) * D_MODEL;
        #pragma unroll
        for (int n = 0; n < 16; ++n)
            obase[(kh*16 + n)*16 + lr] = o[n][r] * inv;
    }
}

extern "C" void kernel_launch(void* const* d_in, const int* in_sizes, int n_in,
                              void* d_out, int out_size, void* d_ws, size_t ws_size,
                              hipStream_t stream) {
    const float* x = (const float*)d_in[0];
    const float* w = (const float*)d_in[1];
    const float* b = (const float*)d_in[2];
    float* out = (float*)d_out;
    unsigned short* node_bf  = (unsigned short*)d_ws;
    unsigned short* nodeT_bf = node_bf + (size_t)M_TOT * D_MODEL;
    const size_t out_bytes = (size_t)out_size * 4;

    // canary: if nothing below writes d_out, absmax ~= 48.6
    (void)hipMemsetAsync(d_out, 0x42, out_bytes, stream);

    if (d_ws == 0 || ws_size < WS_NEEDED) {
        (void)hipMemsetAsync(d_out, 0x4F, out_bytes, stream);   // ws sentinel
        return;
    }

    (void)hipGetLastError();
    proj_kernel<<<dim3(M_TOT/128, D_MODEL/128), dim3(256), 0, stream>>>(x, w, b, node_bf, nodeT_bf);
    hipError_t ep = hipGetLastError();
    flash_kernel<<<dim3(SEQ/64, BATCH), dim3(512), 0, stream>>>(node_bf, nodeT_bf, out);
    hipError_t ef = hipGetLastError();

    if (ep != hipSuccess) {
        (void)hipMemsetAsync(d_out, 0x49, out_bytes, stream);   // proj launch fail
    } else if (ef != hipSuccess) {
        (void)hipMemsetAsync(d_out, 0x4B, out_bytes, stream);   // flash launch fail
    }
}

// Round 12
// 331.029 us; speedup vs baseline: 1.1632x; 1.1632x over previous
//
#include <hip/hip_runtime.h>

#define D_MODEL 512
#define SEQ     4096
#define BATCH   4
#define M_TOT   (BATCH*SEQ)   // 16384
#define NT      (SEQ/32)      // 128 key tiles
#define WS_NEEDED ((size_t)2 * M_TOT * D_MODEL * 2)   // node_bf + nodeT_bf: 32 MiB

typedef float  f32x4  __attribute__((ext_vector_type(4)));
typedef __bf16 bf16x8 __attribute__((ext_vector_type(8)));

// lgkm-only barrier: syncs LDS data across waves WITHOUT draining vmcnt,
// so in-flight global_load_lds prefetches survive across it.
#define LGKM_BARRIER() asm volatile("s_waitcnt lgkmcnt(0)\n\ts_barrier" ::: "memory")

union FU { float f; unsigned int u; };
__device__ __forceinline__ unsigned short f_to_bf16(float f) {
    FU c; c.f = f;
    unsigned int r = c.u + 0x7fffu + ((c.u >> 16) & 1u);   // RNE
    return (unsigned short)(r >> 16);
}

// split fp32 pair -> packed hi (truncated top16) + packed lo (RNE bf16 of
// exact residual). hi+lo reproduces x to ~2^-17 relative.
__device__ __forceinline__ void split_pack(float f0, float f1,
        unsigned int& hp, unsigned int& lp) {
    FU u0, u1; u0.f = f0; u1.f = f1;
    unsigned int h0 = u0.u & 0xFFFF0000u, h1 = u1.u & 0xFFFF0000u;
    hp = (h0 >> 16) | h1;
    FU t0, t1; t0.u = h0; t1.u = h1;
    float l0 = f0 - t0.f, l1 = f1 - t1.f;       // exact (Sterbenz)
    lp = (unsigned)f_to_bf16(l0) | ((unsigned)f_to_bf16(l1) << 16);
}

// ---- DPP cross-lane (VALU pipe, NOT the DS pipe like __shfl_xor) ----
// 16-lane butterfly, pairings commutative-identical to shfl_xor(1,2,4,8):
// results BITWISE identical to a shfl tree.
template<int CTRL>
__device__ __forceinline__ float dpp_mov(float x) {
    union { float f; int i; } u, r;
    u.f = x;
    r.i = __builtin_amdgcn_update_dpp(u.i, u.i, CTRL, 0xF, 0xF, false);
    return r.f;
}
__device__ __forceinline__ float red_max16(float x) {
    x = fmaxf(x, dpp_mov<0xB1>(x));
    x = fmaxf(x, dpp_mov<0x4E>(x));
    x = fmaxf(x, dpp_mov<0x141>(x));
    x = fmaxf(x, dpp_mov<0x140>(x));
    return x;
}
__device__ __forceinline__ float red_sum16(float x) {
    x += dpp_mov<0xB1>(x);
    x += dpp_mov<0x4E>(x);
    x += dpp_mov<0x141>(x);
    x += dpp_mov<0x140>(x);
    return x;
}

// -------- K1: node_bf = relu(x @ W^T + b) (bf16), + transposed copy --------
// v7 (proven ~115us; v11's LDS-free variant regressed to ~141 — reverted):
// split-bf16 MFMA GEMM. x = x_hi + x_lo, W = W_hi + W_lo; x@W^T = hi*hi +
// hi*lo + lo*hi via 3 bf16 MFMAs, fp32 accum. LDS staging splits each
// element ONCE per block, shared by 4 waves.
extern "C" __global__ __launch_bounds__(256, 2) void proj_kernel(
        const float* __restrict__ x, const float* __restrict__ w,
        const float* __restrict__ bias,
        unsigned short* __restrict__ node_bf, unsigned short* __restrict__ nodeT_bf) {
    __shared__ unsigned short Ah[128][40], Al[128][40], Bh[128][40], Bl[128][40];
    const int tid  = threadIdx.x;
    const int lane = tid & 63;
    const int wv   = tid >> 6;        // 0..3
    const int lr   = lane & 15;
    const int quad = lane >> 4;
    const int row0 = blockIdx.x * 128;
    const int col0 = blockIdx.y * 128;
    const int wm   = (wv & 1) * 64;
    const int wn   = (wv >> 1) * 64;

    f32x4 acc[4][4];
    #pragma unroll
    for (int i = 0; i < 4; ++i)
        #pragma unroll
        for (int j = 0; j < 4; ++j) acc[i][j] = (f32x4){0.f,0.f,0.f,0.f};

    for (int kc = 0; kc < D_MODEL; kc += 32) {
        #pragma unroll
        for (int i = 0; i < 2; ++i) {
            int idx = i*256 + tid;
            int r = idx >> 2, c8 = (idx & 3) * 8;
            const float* xp = x + (size_t)(row0 + r)*D_MODEL + kc + c8;
            const float* wp = w + (size_t)(col0 + r)*D_MODEL + kc + c8;
            float4 a0 = *(const float4*)(xp);
            float4 a1 = *(const float4*)(xp + 4);
            float4 b0 = *(const float4*)(wp);
            float4 b1 = *(const float4*)(wp + 4);
            uint4 hA, lA, hB, lB;
            split_pack(a0.x, a0.y, hA.x, lA.x);
            split_pack(a0.z, a0.w, hA.y, lA.y);
            split_pack(a1.x, a1.y, hA.z, lA.z);
            split_pack(a1.z, a1.w, hA.w, lA.w);
            split_pack(b0.x, b0.y, hB.x, lB.x);
            split_pack(b0.z, b0.w, hB.y, lB.y);
            split_pack(b1.x, b1.y, hB.z, lB.z);
            split_pack(b1.z, b1.w, hB.w, lB.w);
            *(uint4*)&Ah[r][c8] = hA;
            *(uint4*)&Al[r][c8] = lA;
            *(uint4*)&Bh[r][c8] = hB;
            *(uint4*)&Bl[r][c8] = lB;
        }
        __syncthreads();

        bf16x8 ah[4], al[4], bh[4], bl[4];
        #pragma unroll
        for (int i = 0; i < 4; ++i) {
            ah[i] = *(const bf16x8*)&Ah[wm + i*16 + lr][quad*8];
            al[i] = *(const bf16x8*)&Al[wm + i*16 + lr][quad*8];
            bh[i] = *(const bf16x8*)&Bh[wn + i*16 + lr][quad*8];
            bl[i] = *(const bf16x8*)&Bl[wn + i*16 + lr][quad*8];
        }
        #pragma unroll
        for (int i = 0; i < 4; ++i)
            #pragma unroll
            for (int j = 0; j < 4; ++j) {
                acc[i][j] = __builtin_amdgcn_mfma_f32_16x16x32_bf16(al[i], bh[j], acc[i][j], 0, 0, 0);
                acc[i][j] = __builtin_amdgcn_mfma_f32_16x16x32_bf16(ah[i], bl[j], acc[i][j], 0, 0, 0);
                acc[i][j] = __builtin_amdgcn_mfma_f32_16x16x32_bf16(ah[i], bh[j], acc[i][j], 0, 0, 0);
            }
        __syncthreads();
    }

    // epilogue: +bias, relu, RNE->bf16, write node + transposed copy.
    // C/D layout (m89): row = quad*4 + r, col = lr.
    #pragma unroll
    for (int j = 0; j < 4; ++j) {
        int col = col0 + wn + j*16 + lr;
        float bv = bias[col];
        #pragma unroll
        for (int i = 0; i < 4; ++i) {
            #pragma unroll
            for (int r = 0; r < 4; ++r) {
                float v = acc[i][j][r] + bv;
                v = v > 0.0f ? v : 0.0f;
                unsigned short us = f_to_bf16(v);
                int row = row0 + wm + i*16 + quad*4 + r;
                node_bf[(size_t)row*D_MODEL + col] = us;
                int b = row >> 12, si = row & 4095;
                nodeT_bf[((size_t)(b*D_MODEL + col))*SEQ + si] = us;
            }
        }
    }
}

// -------- K2: flash attention via MFMA, out(fp32) --------
// v12 = v10 with TWO sync points per iter instead of three:
//  * top:   issue stageK(idx+1) -> s_waitcnt vmcnt(4) (waits only
//           stage(idx); stage(idx+1) stays in flight) + s_barrier (epoch).
//           Safe: every wave's QK reads of the buffer being rewritten
//           drained at the previous LGKM#1 (lgkmcnt(0) before arrival).
//  * LGKM#1 after posting Sm AND per-wave live bits; pair skip decision
//           = Lf[wv]|Lf[wv^4] -- identical predicate to v10 (max
//           distributes over OR) -> bit-identical skip set & output.
//  * end-of-iter __syncthreads DELETED (post-loop barrier added before
//           the l-exchange, which otherwise races).
// Live path unchanged: stageV -> __syncthreads -> PV (rare, ~4/130).
// LDS: 65536 (Ks) + 32768 (Vt) + 5120 (Ps) + 512 (Sm) + 32 (Lf) = 103968 B
extern "C" __global__ __launch_bounds__(512, 2) void flash_kernel(
        const unsigned short* __restrict__ node,
        const unsigned short* __restrict__ nodeT,
        float* __restrict__ out) {
    __shared__ unsigned short Ks[2][32][512];   // [buf][key][d]
    __shared__ unsigned short Vt[512][32];      // [d][key], single buffer
    __shared__ unsigned short Ps[4][16][40];    // [qg][qrow][key], +8 pad
    __shared__ float          Sm[4][2][16];     // [qg][kh][row] exchange buffer
    __shared__ int            Lf[8];            // per-wave live flags
    const int tid  = threadIdx.x;
    const int lane = tid & 63;
    const int wv   = tid >> 6;        // 0..7
    const int qg   = wv & 3;          // qrow group
    const int kh   = wv >> 2;         // key half (QK) / d half (PV)
    const int lr   = lane & 15;
    const int quad = lane >> 4;
    const int bb   = blockIdx.y;
    const int q0   = blockIdx.x * 64;
    const int ktd  = blockIdx.x * 2;  // first of the two diagonal tiles

    const unsigned short* nb  = node  + (size_t)bb * SEQ * D_MODEL;
    const unsigned short* ntb = nodeT + (size_t)bb * D_MODEL * SEQ;

    // Q fragments: A[m=lr][k = t*32 + quad*8 + j]
    bf16x8 qf[16];
    const int qrow = q0 + qg*16 + lr;
    #pragma unroll
    for (int t = 0; t < 16; ++t)
        qf[t] = *reinterpret_cast<const bf16x8*>(&nb[(size_t)qrow*D_MODEL + t*32 + quad*8]);

    f32x4 o[16];                      // 16 qrows x 256 d (own half)
    #pragma unroll
    for (int n = 0; n < 16; ++n) o[n] = (f32x4){0.f,0.f,0.f,0.f};
    float m_run[4] = {-3.0e38f,-3.0e38f,-3.0e38f,-3.0e38f};
    float l_run[4] = {0.f,0.f,0.f,0.f};

    // tile order: [ktd, ktd+1, 0, 1, ..., 127] (prepass then sequential)
    auto ktOf = [&](int i) { return i < 2 ? ktd + i : i - 2; };

    // stage K tile kt into buffer buf (8 waves x 4 rows, 4 loads/wave).
    auto stageK = [&](int kt, int buf) {
        #pragma unroll
        for (int i = 0; i < 4; ++i) {
            int r = wv*4 + i;
            const unsigned short* g = nb + (size_t)(kt*32 + r)*D_MODEL + ((lane ^ (r & 7)) << 3);
            __builtin_amdgcn_global_load_lds(
                (const __attribute__((address_space(1))) unsigned int*)g,
                (__attribute__((address_space(3))) unsigned int*)&Ks[buf][r][0],
                16, 0, 0);
        }
    };
    // stage V tile kt into the single Vt buffer (8 waves x 4 chunks).
    auto stageV = [&](int kt) {
        #pragma unroll
        for (int i = 0; i < 4; ++i) {
            int d0 = (wv*4 + i) * 16;
            int d  = d0 + (lane >> 2);
            const unsigned short* g = ntb + (size_t)d*SEQ + kt*32 + ((((lane & 3) ^ (d & 3))) << 3);
            __builtin_amdgcn_global_load_lds(
                (const __attribute__((address_space(1))) unsigned int*)g,
                (__attribute__((address_space(3))) unsigned int*)&Vt[d0][0],
                16, 0, 0);
        }
    };

    stageK(ktOf(0), 0);   // waited by the first in-loop vmcnt+barrier

    const int kxor = lr & 7;   // K read swizzle ((kh*16+lr)&7 == lr&7)
    const int vxor = lr & 3;   // V read swizzle ((dblk*16+lr)&3 == lr&3)

    for (int idx = 0; idx < NT + 2; ++idx) {
        const int cur = idx & 1;
        const int kt  = ktOf(idx);
        // diag tiles already accumulated by the prepass -> force-skip later
        const bool force = (idx >= 2) && ((kt >> 1) == blockIdx.x);
        const bool more  = (idx + 1 < NT + 2);
        // issue next K tile's loads (writes Ks[cur^1]; all readers of that
        // buffer drained at the previous LGKM#1)
        if (more) stageK(ktOf(idx + 1), cur ^ 1);

        // counted wait: stage(idx) done, stage(idx+1) stays in flight.
        if (more) asm volatile("s_waitcnt vmcnt(4)" ::: "memory");
        else      asm volatile("s_waitcnt vmcnt(0)" ::: "memory");
        __builtin_amdgcn_s_barrier();   // epoch: all waves' stage(idx) done

        // S half = Q K^T (16 qrows x own 16 keys); swizzled K read
        f32x4 sacc = (f32x4){0.f,0.f,0.f,0.f};
        __builtin_amdgcn_s_setprio(1);
        #pragma unroll
        for (int t = 0; t < 16; ++t) {
            bf16x8 kb = *reinterpret_cast<const bf16x8*>(
                &Ks[cur][kh*16 + lr][(((t<<2)|quad) ^ kxor) << 3]);
            sacc = __builtin_amdgcn_mfma_f32_16x16x32_bf16(qf[t], kb, sacc, 0, 0, 0);
        }
        __builtin_amdgcn_s_setprio(0);

        // local 16-lane max per row (DPP tree); post Sm AND own live bit
        float mx[4];
        #pragma unroll
        for (int r = 0; r < 4; ++r) mx[r] = red_max16(sacc[r]);
        bool ol = false;
        #pragma unroll
        for (int r = 0; r < 4; ++r) ol = ol || (mx[r] > m_run[r] - 25.0f);
        const bool own_live = __any(ol) && !force;
        if (lr == 0) {
            #pragma unroll
            for (int r = 0; r < 4; ++r) Sm[qg][kh][quad*4 + r] = mx[r];
        }
        if (lane == 0) Lf[wv] = own_live ? 1 : 0;
        LGKM_BARRIER();   // #1: Sm + Lf visible (vmcnt untouched)

        // pair decision: identical predicate to v10 (max distributes over OR)
        const bool skip = force || ((Lf[wv] | Lf[wv ^ 4]) == 0);

        if (!skip) {
            float alpha[4];
            #pragma unroll
            for (int r = 0; r < 4; ++r) {
                float jm   = fmaxf(mx[r], Sm[qg][kh ^ 1][quad*4 + r]);
                float mnew = fmaxf(m_run[r], jm);
                alpha[r]   = __expf(m_run[r] - mnew);
                float p    = __expf(sacc[r] - mnew);
                m_run[r]   = mnew;
                Ps[qg][quad*4 + r][kh*16 + lr] = f_to_bf16(p);
                float rs   = red_sum16(p);
                l_run[r] = l_run[r]*alpha[r] + rs;
            }
            // skip O-rescale when every alpha is exactly 1.0 (bit-exact skip)
            bool need = !(alpha[0]==1.f && alpha[1]==1.f && alpha[2]==1.f && alpha[3]==1.f);
            if (__any(need)) {
                #pragma unroll
                for (int n = 0; n < 16; ++n) {
                    #pragma unroll
                    for (int r = 0; r < 4; ++r) o[n][r] *= alpha[r];
                }
            }
        }

        // block-uniform: does ANY wave need V for this tile?
        const bool block_live = (Lf[0]|Lf[1]|Lf[2]|Lf[3]|Lf[4]|Lf[5]|Lf[6]|Lf[7]) != 0;
        if (block_live) {
            stageV(kt);
            // all-or-none (block-uniform). Drains V DMA before PV reads;
            // also gives Ps write->read visibility for the pair.
            __syncthreads();
            if (!skip) {
                // P fragment: A[m=lr][k=quad*8+j], full 32 keys
                bf16x8 pa = *reinterpret_cast<const bf16x8*>(&Ps[qg][lr][quad*8]);
                // PV: own 16 d-blocks (d = kh*256 ..), swizzled V read
                __builtin_amdgcn_s_setprio(1);
                #pragma unroll
                for (int n = 0; n < 16; ++n) {
                    int dblk = kh*16 + n;
                    bf16x8 vb = *reinterpret_cast<const bf16x8*>(
                        &Vt[dblk*16 + lr][(quad ^ vxor) << 3]);
                    o[n] = __builtin_amdgcn_mfma_f32_16x16x32_bf16(pa, vb, o[n], 0, 0, 0);
                }
                __builtin_amdgcn_s_setprio(0);
            }
        }
        // no end-of-iter barrier: next iter's epoch barrier covers the
        // Ks buffer hazard (readers drained at this iter's LGKM#1).
    }

    // close the loop's final epoch before reusing Sm for the l-exchange
    __syncthreads();

    // final l = own half + partner half (alpha sequence was shared)
    if (lr == 0) {
        #pragma unroll
        for (int r = 0; r < 4; ++r) Sm[qg][kh][quad*4 + r] = l_run[r];
    }
    __syncthreads();
    #pragma unroll
    for (int r = 0; r < 4; ++r) {
        float l_tot = l_run[r] + Sm[qg][kh ^ 1][quad*4 + r];
        float inv   = 1.0f / l_tot;
        int row = q0 + qg*16 + quad*4 + r;
        float* obase = out + ((size_t)bb * SEQ + row) * D_MODEL;
        #pragma unroll
        for (int n = 0; n < 16; ++n)
            obase[(kh*16 + n)*16 + lr] = o[n][r] * inv;
    }
}

extern "C" void kernel_launch(void* const* d_in, const int* in_sizes, int n_in,
                              void* d_out, int out_size, void* d_ws, size_t ws_size,
                              hipStream_t stream) {
    const float* x = (const float*)d_in[0];
    const float* w = (const float*)d_in[1];
    const float* b = (const float*)d_in[2];
    float* out = (float*)d_out;
    unsigned short* node_bf  = (unsigned short*)d_ws;
    unsigned short* nodeT_bf = node_bf + (size_t)M_TOT * D_MODEL;
    const size_t out_bytes = (size_t)out_size * 4;

    // canary: if nothing below writes d_out, absmax ~= 48.6
    (void)hipMemsetAsync(d_out, 0x42, out_bytes, stream);

    if (d_ws == 0 || ws_size < WS_NEEDED) {
        (void)hipMemsetAsync(d_out, 0x4F, out_bytes, stream);   // ws sentinel
        return;
    }

    (void)hipGetLastError();
    proj_kernel<<<dim3(M_TOT/128, D_MODEL/128), dim3(256), 0, stream>>>(x, w, b, node_bf, nodeT_bf);
    hipError_t ep = hipGetLastError();
    flash_kernel<<<dim3(SEQ/64, BATCH), dim3(512), 0, stream>>>(node_bf, nodeT_bf, out);
    hipError_t ef = hipGetLastError();

    if (ep != hipSuccess) {
        (void)hipMemsetAsync(d_out, 0x49, out_bytes, stream);   // proj launch fail
    } else if (ef != hipSuccess) {
        (void)hipMemsetAsync(d_out, 0x4B, out_bytes, stream);   // flash launch fail
    }
}